// Round 3
// baseline (691.087 us; speedup 1.0000x reference)
//
#include <hip/hip_runtime.h>
#include <hip/hip_fp16.h>

typedef _Float16 f16;
typedef _Float16 f16x4 __attribute__((ext_vector_type(4)));
typedef _Float16 f16x8 __attribute__((ext_vector_type(8)));
typedef float    f32x4 __attribute__((ext_vector_type(4)));

#define T_STEPS 2048
#define BATCH   16
#define DIM     1024
#define M_TOTAL (T_STEPS * BATCH)  // 32768

// ---------------------------------------------------------------------------
// async global->LDS (16B per lane). LDS dest must be wave-uniform base;
// hardware adds lane*16 to the LDS destination. Global address is per-lane.
__device__ __forceinline__ void async16(void* lds, const void* g) {
  __builtin_amdgcn_global_load_lds(
      (const __attribute__((address_space(1))) void*)g,
      (__attribute__((address_space(3))) void*)lds, 16, 0, 0);
}

#define WAITV_(n) asm volatile("s_waitcnt vmcnt(" #n ")" ::: "memory")
#define WAITV(n) WAITV_(n)

// ---------------------------------------------------------------------------
// f32 -> f16 convert, 8 elems/thread
__global__ void cvt_kernel(const float* __restrict__ src, f16* __restrict__ dst,
                           int n8) {
  int i = blockIdx.x * 256 + threadIdx.x;
  if (i >= n8) return;
  const float4* s4 = reinterpret_cast<const float4*>(src);
  float4 a = s4[2 * i], b = s4[2 * i + 1];
  f16x8 o;
  o[0] = (f16)a.x; o[1] = (f16)a.y; o[2] = (f16)a.z; o[3] = (f16)a.w;
  o[4] = (f16)b.x; o[5] = (f16)b.y; o[6] = (f16)b.z; o[7] = (f16)b.w;
  *reinterpret_cast<f16x8*>(dst + (size_t)i * 8) = o;
}

// ---------------------------------------------------------------------------
// Dual GEMM: C1[m,e] = sum_d x[m,d]*W[e,d] ; C2 likewise vs W_g.
// Epilogue writes P[m,e] = (C1 + b[e]) * sigmoid(C2 + bg[e]) as f16.
__global__ __launch_bounds__(256, 2)
void dual_gemm(const f16* __restrict__ xh, const f16* __restrict__ wh,
               const f16* __restrict__ wgh, const float* __restrict__ bias,
               const float* __restrict__ biasg, f16* __restrict__ P) {
  __shared__ f16 As[128 * 32];
  __shared__ f16 Bs[128 * 32];
  __shared__ f16 Gs[128 * 32];

  const int tid = threadIdx.x;
  const int bid = blockIdx.x;
  const int swz = ((bid & 7) << 8) | (bid >> 3);
  const int m0 = (swz >> 3) * 128;
  const int e0 = (swz & 7) * 128;

  const int lane = tid & 63;
  const int wave = tid >> 6;
  const int wrow = (wave >> 1) * 64;
  const int wcol = (wave & 1) * 64;
  const int fr = lane & 15;
  const int fc = lane >> 4;

  f32x4 acc1[4][4], acc2[4][4];
#pragma unroll
  for (int i = 0; i < 4; ++i)
#pragma unroll
    for (int j = 0; j < 4; ++j) {
      acc1[i][j] = {0.f, 0.f, 0.f, 0.f};
      acc2[i][j] = {0.f, 0.f, 0.f, 0.f};
    }

  const int    srow  = tid >> 2;
  const size_t sbyte = (size_t)(tid & 3) * 16;
  const char* ga = (const char*)xh  + ((size_t)(m0 + srow)) * 2048 + sbyte;
  const char* gb = (const char*)wh  + ((size_t)(e0 + srow)) * 2048 + sbyte;
  const char* gg = (const char*)wgh + ((size_t)(e0 + srow)) * 2048 + sbyte;
  char* la = (char*)&As[0] + (size_t)wave * 1024;
  char* lb = (char*)&Bs[0] + (size_t)wave * 1024;
  char* lg = (char*)&Gs[0] + (size_t)wave * 1024;

  for (int kk = 0; kk < 1024; kk += 32) {
    const size_t ko = (size_t)kk * 2;
    async16(la,        ga + ko);
    async16(la + 4096, ga + ko + (size_t)64 * 2048);
    async16(lb,        gb + ko);
    async16(lb + 4096, gb + ko + (size_t)64 * 2048);
    async16(lg,        gg + ko);
    async16(lg + 4096, gg + ko + (size_t)64 * 2048);
    asm volatile("s_waitcnt vmcnt(0)" ::: "memory");
    __syncthreads();

    f16x8 af[4], bf[4], gf[4];
#pragma unroll
    for (int i = 0; i < 4; ++i) {
      af[i] = *reinterpret_cast<const f16x8*>(&As[(wrow + i * 16 + fr) * 32 + fc * 8]);
      bf[i] = *reinterpret_cast<const f16x8*>(&Bs[(wcol + i * 16 + fr) * 32 + fc * 8]);
      gf[i] = *reinterpret_cast<const f16x8*>(&Gs[(wcol + i * 16 + fr) * 32 + fc * 8]);
    }
#pragma unroll
    for (int mi = 0; mi < 4; ++mi)
#pragma unroll
      for (int ni = 0; ni < 4; ++ni) {
        acc1[mi][ni] = __builtin_amdgcn_mfma_f32_16x16x32_f16(af[mi], bf[ni], acc1[mi][ni], 0, 0, 0);
        acc2[mi][ni] = __builtin_amdgcn_mfma_f32_16x16x32_f16(af[mi], gf[ni], acc2[mi][ni], 0, 0, 0);
      }
    __syncthreads();
  }

#pragma unroll
  for (int ni = 0; ni < 4; ++ni) {
    const int e = e0 + wcol + ni * 16 + fr;
    const float bb  = bias[e];
    const float bbg = biasg[e];
#pragma unroll
    for (int mi = 0; mi < 4; ++mi) {
      const int mrow = m0 + wrow + mi * 16 + fc * 4;
#pragma unroll
      for (int j = 0; j < 4; ++j) {
        float z1 = acc1[mi][ni][j] + bb;
        float z2 = acc2[mi][ni][j] + bbg;
        float s  = 1.0f / (1.0f + __expf(-z2));
        P[(size_t)(mrow + j) * DIM + e] = (f16)(z1 * s);
      }
    }
  }
}

// ---------------------------------------------------------------------------
// DPP-based wave64 sum: after shr 1/2/4/8 + bcast15/31, lane 63 = total
template <int CTRL>
__device__ __forceinline__ float dpp_add(float x) {
  int m = __builtin_amdgcn_update_dpp(0, __float_as_int(x), CTRL, 0xf, 0xf, true);
  return x + __int_as_float(m);
}

// ---------------------------------------------------------------------------
// Sequential scan, one wave per batch row. h in 16 f32 regs/lane
// (element d = c*256 + lane*4 + j). P rows prefetched through an 8-slot LDS
// ring via global_load_lds (no dest VGPRs -> compiler cannot unwind the
// pipeline), consumed one step ahead into registers so ds_read latency
// overlaps compute. Counted vmcnt per step (stores share the FIFO: 4/step).
//
// vm FIFO per step: 2 gload_lds + 4 stores = 6 entries.
// Steady state wait for slot t+1 (issued at step t-6):
//   4 stores (t-6) + 5 steps * 6 = 34  -> vmcnt(34)
// Steps 0..5: slot t+1 from prologue, precise = 10+4t -> use stricter 10.
__global__ __launch_bounds__(64)
void scan_kernel(const f16* __restrict__ P, const float* __restrict__ h0,
                 float* __restrict__ hout) {
  __shared__ f16 ring[8 * DIM];  // 8 slots x 2KB
  const int b = blockIdx.x;
  const int lane = threadIdx.x;

  char* ring_b = (char*)&ring[0];
  const f16x4* ring4 = (const f16x4*)&ring[0];
  const char* pBase = (const char*)P + (size_t)b * DIM * 2;  // + t*32768

  float h[16];
  {
    const float4* s = reinterpret_cast<const float4*>(h0 + b * DIM);
    float4* d = reinterpret_cast<float4*>(hout + b * DIM);  // h[0] = h0
#pragma unroll
    for (int c = 0; c < 4; ++c) {
      float4 v = s[c * 64 + lane];
      h[c * 4 + 0] = v.x; h[c * 4 + 1] = v.y;
      h[c * 4 + 2] = v.z; h[c * 4 + 3] = v.w;
      d[c * 64 + lane] = v;
    }
  }

  // prologue: fill slots 0..6 (14 gload_lds)
#pragma unroll
  for (int s = 0; s < 7; ++s) {
    const char* g = pBase + (size_t)s * (BATCH * DIM * 2) + (size_t)lane * 16;
    async16(ring_b + s * 2048, g);
    async16(ring_b + s * 2048 + 1024, g + 1024);
  }
  WAITV(12);  // slot 0 landed (12 newer loads outstanding)

  f16x4 pA[4], pN[4];
#pragma unroll
  for (int c = 0; c < 4; ++c) pA[c] = ring4[c * 64 + lane];

#define SCAN_STEP(CUR, NXT, T, WN)                                            \
  {                                                                           \
    WAITV(WN); /* slot (T)+1 landed */                                        \
    const int slotn = ((T) + 1) & 7;                                          \
    _Pragma("unroll")                                                         \
    for (int c = 0; c < 4; ++c) NXT[c] = ring4[slotn * 256 + c * 64 + lane];  \
    /* prefetch row (T)+7 into slot freed last step ((T)-1)&7 */              \
    const int tw = ((T) + 7) & (T_STEPS - 1);                                 \
    const char* g = pBase + (size_t)tw * (BATCH * DIM * 2) + (size_t)lane * 16; \
    char* ls = ring_b + (((T)-1) & 7) * 2048;                                 \
    async16(ls, g);                                                           \
    async16(ls + 1024, g + 1024);                                             \
    __builtin_amdgcn_sched_barrier(0);                                        \
    float v[16];                                                              \
    _Pragma("unroll")                                                         \
    for (int c = 0; c < 4; ++c) {                                             \
      _Pragma("unroll")                                                       \
      for (int j = 0; j < 4; ++j)                                             \
        v[c * 4 + j] = fmaf((float)CUR[c][j], 1.0f, h[c * 4 + j]);            \
    }                                                                         \
    float s0 = 0.f, s1 = 0.f, s2 = 0.f, s3 = 0.f;                             \
    _Pragma("unroll")                                                         \
    for (int j = 0; j < 4; ++j) {                                             \
      s0 = fmaf(v[j],      v[j],      s0);                                    \
      s1 = fmaf(v[4 + j],  v[4 + j],  s1);                                    \
      s2 = fmaf(v[8 + j],  v[8 + j],  s2);                                    \
      s3 = fmaf(v[12 + j], v[12 + j], s3);                                    \
    }                                                                         \
    float ss = (s0 + s1) + (s2 + s3);                                         \
    ss = dpp_add<0x111>(ss);                                                  \
    ss = dpp_add<0x112>(ss);                                                  \
    ss = dpp_add<0x114>(ss);                                                  \
    ss = dpp_add<0x118>(ss);                                                  \
    ss = dpp_add<0x142>(ss);                                                  \
    ss = dpp_add<0x143>(ss);                                                  \
    float tot = __int_as_float(__builtin_amdgcn_readlane(__float_as_int(ss), 63)); \
    float r = __builtin_amdgcn_rsqf(fmaf(tot, 1.0f / DIM, 1e-6f));            \
    _Pragma("unroll")                                                         \
    for (int i = 0; i < 16; ++i) h[i] = v[i] * r;                             \
    float4* hr = reinterpret_cast<float4*>(hout + ((size_t)((T) + 1) * BATCH + b) * DIM); \
    _Pragma("unroll")                                                         \
    for (int c = 0; c < 4; ++c)                                               \
      hr[c * 64 + lane] =                                                     \
          make_float4(h[c * 4], h[c * 4 + 1], h[c * 4 + 2], h[c * 4 + 3]);    \
  }

  // peeled warmup: steps 0..5 (slot t+1 still from prologue)
  SCAN_STEP(pA, pN, 0, 10);
  SCAN_STEP(pN, pA, 1, 10);
  SCAN_STEP(pA, pN, 2, 10);
  SCAN_STEP(pN, pA, 3, 10);
  SCAN_STEP(pA, pN, 4, 10);
  SCAN_STEP(pN, pA, 5, 10);

  for (int t = 6; t < T_STEPS; t += 2) {
    SCAN_STEP(pA, pN, t, 34);
    SCAN_STEP(pN, pA, t + 1, 34);
  }
#undef SCAN_STEP
}

// ---------------------------------------------------------------------------
// out = h * silu(h) = h^2 * sigmoid(h), elementwise over hs (h rows 1..T)
__global__ void silu_out_kernel(const float* __restrict__ hsrc,
                                float* __restrict__ out, int n4) {
  int stride = gridDim.x * blockDim.x;
  for (int i = blockIdx.x * blockDim.x + threadIdx.x; i < n4; i += stride) {
    float4 v = reinterpret_cast<const float4*>(hsrc)[i];
    float4 o;
    o.x = v.x * v.x / (1.0f + __expf(-v.x));
    o.y = v.y * v.y / (1.0f + __expf(-v.y));
    o.z = v.z * v.z / (1.0f + __expf(-v.z));
    o.w = v.w * v.w / (1.0f + __expf(-v.w));
    reinterpret_cast<float4*>(out)[i] = o;
  }
}

// ---------------------------------------------------------------------------
extern "C" void kernel_launch(void* const* d_in, const int* in_sizes, int n_in,
                              void* d_out, int out_size, void* d_ws, size_t ws_size,
                              hipStream_t stream) {
  const float* x  = (const float*)d_in[0];  // [T,B,D]
  const float* h0 = (const float*)d_in[1];  // [B,D]
  const float* W  = (const float*)d_in[2];  // [D,D]
  const float* Wg = (const float*)d_in[3];  // [D,D]
  const float* bb = (const float*)d_in[4];  // [D]
  const float* bg = (const float*)d_in[5];  // [D]

  float* out  = (float*)d_out;                              // [T,B,D]
  float* hout = out + (size_t)T_STEPS * BATCH * DIM;        // [T+1,B,D]

  char* ws = (char*)d_ws;
  f16* xh  = (f16*)(ws);                                    // 64 MiB
  f16* wh  = (f16*)(ws + (size_t)67108864);                 // 2 MiB
  f16* wgh = (f16*)(ws + (size_t)69206016);                 // 2 MiB
  f16* P   = (f16*)(ws + (size_t)71303168);                 // 64 MiB

  cvt_kernel<<<16384, 256, 0, stream>>>(x,  xh,  4194304);
  cvt_kernel<<<512,   256, 0, stream>>>(W,  wh,  131072);
  cvt_kernel<<<512,   256, 0, stream>>>(Wg, wgh, 131072);

  dual_gemm<<<2048, 256, 0, stream>>>(xh, wh, wgh, bb, bg, P);

  scan_kernel<<<BATCH, 64, 0, stream>>>(P, h0, hout);

  silu_out_kernel<<<2048, 256, 0, stream>>>(hout + BATCH * DIM, out, 8388608);
}